// Round 1
// baseline (172.539 us; speedup 1.0000x reference)
//
#include <hip/hip_runtime.h>
#include <math.h>

#define VOCAB 2048
#define TPB   256
#define NBINS 64
// bin scale: 64 bins cover (m - v) in [0, 64/6 = 10.667); kept tokens provably
// have m - v <= ln(2048/0.05) = 10.62, so the top-p crossing is always inside.
#define BIN_SCALE 6.0f

__global__ __launch_bounds__(TPB) void sampler_kernel(
    const float* __restrict__ logits,
    const float* __restrict__ uni,
    float* __restrict__ out_idx,    // [B]   sampled index as float
    float* __restrict__ out_probs)  // [B,V] filtered softmax
{
    const int row  = blockIdx.x;
    const int t    = threadIdx.x;
    const int lane = t & 63;
    const int wid  = t >> 6;

    __shared__ float  s_bins[NBINS];
    __shared__ float  s_wf[4];
    __shared__ double s_wd[4];
    __shared__ float  s_m;
    __shared__ double s_S;
    __shared__ double s_SK;
    __shared__ double s_cumBefore;
    __shared__ int    s_bstar;
    __shared__ int    s_cnt;
    __shared__ float  s_cv[VOCAB];   // boundary-bin candidate values
    __shared__ float  s_ce[VOCAB];   // boundary-bin candidate exps
    __shared__ float  s_rz[4];
    __shared__ int    s_ri[4];

    const float* lrow = logits   + (size_t)row * VOCAB;
    const float* urow = uni      + (size_t)row * VOCAB;
    float*       prow = out_probs + (size_t)row * VOCAB;

    if (t < NBINS) s_bins[t] = 0.0f;
    if (t == 0)    s_cnt = 0;

    // ---- load + temperature scale (fp32 division to match reference) ----
    float4 a0 = *(const float4*)(lrow + 4 * t);
    float4 a1 = *(const float4*)(lrow + VOCAB / 2 + 4 * t);
    float s[8];
    s[0] = a0.x / 0.8f; s[1] = a0.y / 0.8f; s[2] = a0.z / 0.8f; s[3] = a0.w / 0.8f;
    s[4] = a1.x / 0.8f; s[5] = a1.y / 0.8f; s[6] = a1.z / 0.8f; s[7] = a1.w / 0.8f;

    // ---- block max ----
    float lm = s[0];
    #pragma unroll
    for (int j = 1; j < 8; j++) lm = fmaxf(lm, s[j]);
    #pragma unroll
    for (int off = 32; off; off >>= 1) lm = fmaxf(lm, __shfl_down(lm, off));
    if (lane == 0) s_wf[wid] = lm;
    __syncthreads();                                    // B1
    if (t == 0) s_m = fmaxf(fmaxf(s_wf[0], s_wf[1]), fmaxf(s_wf[2], s_wf[3]));
    __syncthreads();                                    // B2
    const float m = s_m;

    // ---- exp, total sum (double), histogram of exp-mass by value bin ----
    float e[8];
    int   bin[8];
    float psum = 0.0f;
    #pragma unroll
    for (int j = 0; j < 8; j++) {
        e[j] = expf(s[j] - m);
        psum += e[j];
        bin[j] = (int)((m - s[j]) * BIN_SCALE);         // >= 0; >=NBINS => removed for sure
        if (bin[j] < NBINS) atomicAdd(&s_bins[bin[j]], e[j]);
    }
    double dp = (double)psum;
    #pragma unroll
    for (int off = 32; off; off >>= 1) dp += __shfl_down(dp, off);
    if (lane == 0) s_wd[wid] = dp;
    __syncthreads();                                    // B3
    if (t == 0) {
        double S  = s_wd[0] + s_wd[1] + s_wd[2] + s_wd[3];
        double pS = 0.95 * S;
        // scan bins top-down; boundary bin = first bin where cum exp-mass > p*S
        double cum = 0.0, cb = 0.0;
        int bstar = -1;
        for (int b = 0; b < NBINS; b++) {
            double nc = cum + (double)s_bins[b];
            if (bstar < 0 && nc > pS) { bstar = b; cb = cum; }
            cum = nc;
        }
        if (bstar < 0) { bstar = NBINS - 1; cb = cum - (double)s_bins[NBINS - 1]; }
        s_S = S; s_bstar = bstar; s_cumBefore = cb;
    }
    __syncthreads();                                    // B4
    const double S         = s_S;
    const double pS        = 0.95 * S;
    const int    bstar     = s_bstar;
    const double cumBefore = s_cumBefore;

    // ---- compact boundary-bin candidates to LDS ----
    #pragma unroll
    for (int j = 0; j < 8; j++) {
        if (bin[j] == bstar) {
            int pos = atomicAdd(&s_cnt, 1);
            s_cv[pos] = s[j];
            s_ce[pos] = e[j];
        }
    }
    __syncthreads();                                    // B5
    const int cnt = s_cnt;

    // ---- keep decision: kept <=> sum of exp over strictly-greater values <= p*S ----
    unsigned keptMask = 0;
    float    kpsum    = 0.0f;
    #pragma unroll
    for (int j = 0; j < 8; j++) {
        bool kept;
        if (bin[j] < bstar)      kept = true;
        else if (bin[j] > bstar) kept = false;
        else {
            float part = 0.0f;
            for (int i = 0; i < cnt; i++)
                if (s_cv[i] > s[j]) part += s_ce[i];    // broadcast reads, conflict-free
            kept = (cumBefore + (double)part) <= pS;
        }
        if (kept) { keptMask |= (1u << j); kpsum += e[j]; }
    }

    // ---- kept-sum (softmax denominator of filtered row) ----
    double dk = (double)kpsum;
    #pragma unroll
    for (int off = 32; off; off >>= 1) dk += __shfl_down(dk, off);
    if (lane == 0) s_wd[wid] = dk;
    __syncthreads();                                    // B6
    if (t == 0) s_SK = s_wd[0] + s_wd[1] + s_wd[2] + s_wd[3];
    __syncthreads();                                    // B7
    const float SK = (float)s_SK;

    // ---- write probs ----
    float4 p0, p1;
    p0.x = (keptMask & 0x01) ? e[0] / SK : 0.0f;
    p0.y = (keptMask & 0x02) ? e[1] / SK : 0.0f;
    p0.z = (keptMask & 0x04) ? e[2] / SK : 0.0f;
    p0.w = (keptMask & 0x08) ? e[3] / SK : 0.0f;
    p1.x = (keptMask & 0x10) ? e[4] / SK : 0.0f;
    p1.y = (keptMask & 0x20) ? e[5] / SK : 0.0f;
    p1.z = (keptMask & 0x40) ? e[6] / SK : 0.0f;
    p1.w = (keptMask & 0x80) ? e[7] / SK : 0.0f;
    *(float4*)(prow + 4 * t)             = p0;
    *(float4*)(prow + VOCAB / 2 + 4 * t) = p1;

    // ---- Gumbel-max sample over kept tokens ----
    float4 u0 = *(const float4*)(urow + 4 * t);
    float4 u1 = *(const float4*)(urow + VOCAB / 2 + 4 * t);
    float uu[8] = {u0.x, u0.y, u0.z, u0.w, u1.x, u1.y, u1.z, u1.w};
    float bz = -INFINITY;
    int   bi = 0x7fffffff;
    #pragma unroll
    for (int j = 0; j < 8; j++) {
        if ((keptMask >> j) & 1u) {
            float g   = -logf(-logf(uu[j]));
            float z   = s[j] + g;
            int   idx = (j < 4) ? (4 * t + j) : (VOCAB / 2 + 4 * t + (j - 4));
            if (z > bz || (z == bz && idx < bi)) { bz = z; bi = idx; }
        }
    }
    #pragma unroll
    for (int off = 32; off; off >>= 1) {
        float oz = __shfl_down(bz, off);
        int   oi = __shfl_down(bi, off);
        if (oz > bz || (oz == bz && oi < bi)) { bz = oz; bi = oi; }
    }
    if (lane == 0) { s_rz[wid] = bz; s_ri[wid] = bi; }
    __syncthreads();                                    // B8
    if (t == 0) {
        float z0 = s_rz[0]; int i0 = s_ri[0];
        for (int w = 1; w < 4; w++) {
            if (s_rz[w] > z0 || (s_rz[w] == z0 && s_ri[w] < i0)) { z0 = s_rz[w]; i0 = s_ri[w]; }
        }
        out_idx[row] = (float)i0;
    }
}

extern "C" void kernel_launch(void* const* d_in, const int* in_sizes, int n_in,
                              void* d_out, int out_size, void* d_ws, size_t ws_size,
                              hipStream_t stream) {
    const float* logits = (const float*)d_in[0];
    const float* u      = (const float*)d_in[1];
    const int B = in_sizes[0] / VOCAB;   // 8192
    float* out_idx   = (float*)d_out;          // sampled [B,1] flattened, in return order
    float* out_probs = (float*)d_out + B;      // probs [B,V]
    sampler_kernel<<<B, TPB, 0, stream>>>(logits, u, out_idx, out_probs);
}

// Round 2
// 164.498 us; speedup vs baseline: 1.0489x; 1.0489x over previous
//
#include <hip/hip_runtime.h>
#include <math.h>

#define VOCAB 2048
#define TPB   256
#define NBINS 64
// 64 bins cover (m - v) in [0, 64/6 = 10.667); kept tokens provably have
// m - v <= ln(2048/0.05) = 10.62, so the top-p crossing is always inside.
#define BIN_SCALE 6.0f

typedef float vf4 __attribute__((ext_vector_type(4)));

__global__ __launch_bounds__(TPB, 8) void sampler_kernel(
    const float* __restrict__ logits,
    const float* __restrict__ uni,
    float* __restrict__ out_idx,    // [B]   sampled index as float
    float* __restrict__ out_probs)  // [B,V] filtered softmax
{
    const int row  = blockIdx.x;
    const int t    = threadIdx.x;
    const int lane = t & 63;
    const int wid  = t >> 6;

    __shared__ float  s_bins[NBINS];
    __shared__ float  s_wf[4];
    __shared__ double s_wd[4];
    __shared__ float  s_wk[4];
    __shared__ unsigned long long s_key[4];
    __shared__ double s_S, s_cumBefore;
    __shared__ int    s_bstar, s_cnt, s_cnt2;
    __shared__ float  s_cv[VOCAB];   // phase A: boundary-bin values; phase B: kept values
    __shared__ float  s_ce[VOCAB];   // phase A: boundary-bin exps;   phase B: kept idx (bits)

    const float* lrow = logits    + (size_t)row * VOCAB;
    const float* urow = uni       + (size_t)row * VOCAB;
    float*       prow = out_probs + (size_t)row * VOCAB;

    if (t < NBINS) s_bins[t] = 0.0f;
    if (t == 0)    { s_cnt = 0; s_cnt2 = 0; }

    // ---- load + temperature scale (x*1.25f ~ x/0.8f to ~1 ulp) ----
    const vf4 a0 = *(const vf4*)(lrow + 4 * t);
    const vf4 a1 = *(const vf4*)(lrow + VOCAB / 2 + 4 * t);
    float s[8] = {a0.x * 1.25f, a0.y * 1.25f, a0.z * 1.25f, a0.w * 1.25f,
                  a1.x * 1.25f, a1.y * 1.25f, a1.z * 1.25f, a1.w * 1.25f};

    // ---- block max ----
    float lm = s[0];
    #pragma unroll
    for (int j = 1; j < 8; j++) lm = fmaxf(lm, s[j]);
    #pragma unroll
    for (int off = 32; off; off >>= 1) lm = fmaxf(lm, __shfl_down(lm, off));
    if (lane == 0) s_wf[wid] = lm;
    __syncthreads();                                    // B1 (also covers LDS init)
    const float m = fmaxf(fmaxf(s_wf[0], s_wf[1]), fmaxf(s_wf[2], s_wf[3]));

    // ---- exp (fast), total sum (double), exp-mass histogram by value bin ----
    float e[8];
    int   bin[8];
    float psum = 0.0f;
    #pragma unroll
    for (int j = 0; j < 8; j++) {
        e[j] = __expf(s[j] - m);
        psum += e[j];
        bin[j] = (int)((m - s[j]) * BIN_SCALE);
        if (bin[j] < NBINS) atomicAdd(&s_bins[bin[j]], e[j]);
    }
    double dp = (double)psum;
    #pragma unroll
    for (int off = 32; off; off >>= 1) dp += __shfl_down(dp, off);
    if (lane == 0) s_wd[wid] = dp;
    __syncthreads();                                    // B2

    // ---- wave0: parallel prefix-scan of 64 bins, find boundary bin ----
    if (wid == 0) {
        double S  = s_wd[0] + s_wd[1] + s_wd[2] + s_wd[3];
        float  bf = s_bins[lane];
        double c  = (double)bf;
        #pragma unroll
        for (int d = 1; d < 64; d <<= 1) {
            double o = __shfl_up(c, d);
            if (lane >= d) c += o;
        }
        double pS = 0.95 * S;
        unsigned long long ball = __ballot(c > pS);
        int bstar = ball ? (__ffsll(ball) - 1) : (NBINS - 1);
        double excl = c - (double)bf;                   // exclusive prefix
        double cumB = __shfl(excl, bstar);
        if (lane == 0) { s_S = S; s_bstar = bstar; s_cumBefore = cumB; }
    }
    __syncthreads();                                    // B3
    const double pS        = 0.95 * s_S;
    const int    bstar     = s_bstar;
    const double cumBefore = s_cumBefore;

    // ---- compact boundary-bin candidates to LDS ----
    #pragma unroll
    for (int j = 0; j < 8; j++) {
        if (bin[j] == bstar) {
            int pos = atomicAdd(&s_cnt, 1);
            s_cv[pos] = s[j];
            s_ce[pos] = e[j];
        }
    }
    __syncthreads();                                    // B4
    const int cnt = s_cnt;

    // ---- keep decision: kept <=> exp-sum over strictly-greater values <= p*S ----
    unsigned keptMask = 0;
    float    kpsum    = 0.0f;
    #pragma unroll
    for (int j = 0; j < 8; j++) {
        bool kept;
        if (bin[j] < bstar)      kept = true;
        else if (bin[j] > bstar) kept = false;
        else {
            float part = 0.0f;
            for (int i = 0; i < cnt; i++)
                if (s_cv[i] > s[j]) part += s_ce[i];    // broadcast reads, conflict-free
            kept = (cumBefore + (double)part) <= pS;
        }
        if (kept) { keptMask |= (1u << j); kpsum += e[j]; }
    }
    #pragma unroll
    for (int off = 32; off; off >>= 1) kpsum += __shfl_down(kpsum, off);
    if (lane == 0) s_wk[wid] = kpsum;
    __syncthreads();                                    // B5 (keep loop done -> s_cv/s_ce reusable)
    const float SK    = s_wk[0] + s_wk[1] + s_wk[2] + s_wk[3];
    const float invSK = 1.0f / SK;

    // ---- write probs (nontemporal: never re-read) ----
    vf4 p0, p1;
    p0.x = (keptMask & 0x01) ? e[0] * invSK : 0.0f;
    p0.y = (keptMask & 0x02) ? e[1] * invSK : 0.0f;
    p0.z = (keptMask & 0x04) ? e[2] * invSK : 0.0f;
    p0.w = (keptMask & 0x08) ? e[3] * invSK : 0.0f;
    p1.x = (keptMask & 0x10) ? e[4] * invSK : 0.0f;
    p1.y = (keptMask & 0x20) ? e[5] * invSK : 0.0f;
    p1.z = (keptMask & 0x40) ? e[6] * invSK : 0.0f;
    p1.w = (keptMask & 0x80) ? e[7] * invSK : 0.0f;
    __builtin_nontemporal_store(p0, (vf4*)(prow + 4 * t));
    __builtin_nontemporal_store(p1, (vf4*)(prow + VOCAB / 2 + 4 * t));

    // ---- compact KEPT tokens (value, index); gumbel only for these ----
    #pragma unroll
    for (int j = 0; j < 8; j++) {
        if ((keptMask >> j) & 1u) {
            int idx = (j < 4) ? (4 * t + j) : (VOCAB / 2 + 4 * t + (j - 4));
            int pos = atomicAdd(&s_cnt2, 1);
            s_cv[pos] = s[j];
            s_ce[pos] = __int_as_float(idx);
        }
    }
    __syncthreads();                                    // B6
    const int k = s_cnt2;

    // ---- Gumbel-max over kept tokens only (precise lib logf, sparse u gather) ----
    unsigned long long key = 0ull;   // any real z maps above 0
    for (int i = t; i < k; i += TPB) {
        float sv  = s_cv[i];
        int   idx = __float_as_int(s_ce[i]);
        float uv  = urow[idx];
        float g   = -logf(-logf(uv));
        float z   = sv + g;
        unsigned zb = __float_as_uint(z);
        zb = (zb & 0x80000000u) ? ~zb : (zb | 0x80000000u);   // order-preserving map
        unsigned long long kk =
            ((unsigned long long)zb << 32) | (unsigned)(VOCAB - 1 - idx); // min-idx tiebreak
        key = (kk > key) ? kk : key;
    }
    #pragma unroll
    for (int off = 32; off; off >>= 1) {
        unsigned long long ok = __shfl_down(key, off);
        key = (ok > key) ? ok : key;
    }
    if (lane == 0) s_key[wid] = key;
    __syncthreads();                                    // B7
    if (t == 0) {
        unsigned long long k0 = s_key[0];
        #pragma unroll
        for (int w = 1; w < 4; w++) k0 = (s_key[w] > k0) ? s_key[w] : k0;
        out_idx[row] = (float)(VOCAB - 1 - (int)(k0 & 0xFFFFFFFFu));
    }
}

extern "C" void kernel_launch(void* const* d_in, const int* in_sizes, int n_in,
                              void* d_out, int out_size, void* d_ws, size_t ws_size,
                              hipStream_t stream) {
    const float* logits = (const float*)d_in[0];
    const float* u      = (const float*)d_in[1];
    const int B = in_sizes[0] / VOCAB;   // 8192
    float* out_idx   = (float*)d_out;          // sampled [B,1] flattened, in return order
    float* out_probs = (float*)d_out + B;      // probs [B,V]
    sampler_kernel<<<B, TPB, 0, stream>>>(logits, u, out_idx, out_probs);
}